// Round 10
// baseline (276.373 us; speedup 1.0000x reference)
//
#include <hip/hip_runtime.h>
#include <stdint.h>

typedef __attribute__((ext_vector_type(8))) short bf16x8;
typedef __attribute__((ext_vector_type(4))) float f32x4;

#define HH  100   // history length
#define DD  128   // embedding dim d
#define HID 256   // hidden width / concat dim

__device__ __forceinline__ unsigned short f2bf(float f) {
    unsigned int u = __float_as_uint(f);
    u += 0x7fffu + ((u >> 16) & 1u);   // round-to-nearest-even
    return (unsigned short)(u >> 16);
}

// async 1 KB global->LDS per wave: per-lane 16 B from g+lane*16, LDS at uniform base + lane*16
__device__ __forceinline__ void load_lds_1k(const void* g, void* l) {
    __builtin_amdgcn_global_load_lds((const __attribute__((address_space(1))) unsigned int*)g,
                                     (__attribute__((address_space(3))) unsigned int*)l,
                                     16, 0, 0);
}

// Pack W1 (256x256 f32, [n][k]) into MFMA B-fragment order, bf16 (RNE — runs once).
// unit = (st*8+s)*64 + lane holds W1[st*16 + (lane&15)][s*32 + (lane>>4)*8 + j], j=0..7
__global__ void w1_pack(const float* __restrict__ W1, unsigned short* __restrict__ W1p) {
    int unit = blockIdx.x * 256 + threadIdx.x;   // 0..8191
    int lane = unit & 63;
    int s    = (unit >> 6) & 7;
    int st   = unit >> 9;
    int col  = lane & 15, quad = lane >> 4;
    const float* src = W1 + (size_t)(st * 16 + col) * HID + s * 32 + quad * 8;
    union { unsigned short u[8]; bf16x8 v; } o;
    #pragma unroll
    for (int j = 0; j < 8; j++) o.u[j] = f2bf(src[j]);
    *(bf16x8*)(W1p + (size_t)unit * 8) = o.v;
}

// Persistent structure: 256 blocks x 1024 threads = 1 block/CU, 16 waves (50% occ).
// Packed B (128 KB) is staged into LDS ONCE and reused by all 8 elements the
// block processes (2 rounds x 4 wave-groups). Wave (group g, pair p) owns rows
// 32p..32p+31 of group g's element across ALL 256 cols -> score completes
// in-wave (no atomics), and the only barriers are 1 prologue + 1 per round.
__global__ __launch_bounds__(1024) void nais_kernel(
    const int* __restrict__ history,           // [B,HH]
    const int* __restrict__ target,            // [B]
    const int* __restrict__ history_region,    // [B,HH]
    const int* __restrict__ target_region,     // [B]
    const float* __restrict__ target_distance, // [B]
    const float* __restrict__ E_hist,          // [item,128]
    const float* __restrict__ E_tgt,           // [item,128]
    const float* __restrict__ E_reg,           // [region,128]
    const float* __restrict__ E_dist,          // [16,128]
    const float* __restrict__ b1,              // [256]
    const float* __restrict__ w2,              // [256]
    const unsigned short* __restrict__ W1p,    // packed bf16 B-fragments (128 KB)
    float* __restrict__ out,                   // [B]
    int Btot)
{
    __shared__ __align__(16) unsigned short Bf[65536];   // 128 KB: full packed W1
    __shared__ __align__(16) float tgts[2][4][HID];      // [round parity][group]
    __shared__ __align__(16) float b1s[HID];
    __shared__ __align__(16) float w2s[HID];
    __shared__ float score4[2][4][128];                  // [parity][group][row]
    __shared__ float xsum4[2][4][128];
    __shared__ float s_sumE;

    const int blk  = blockIdx.x;               // element base: blk*8
    const int t    = threadIdx.x;
    const int lane = t & 63;
    const int wave = t >> 6;                   // 0..15
    const int p    = wave & 3;                 // row-pair within group (rows 32p..32p+31)
    const int g    = wave >> 2;                // group 0..3 (one element per round)
    const int col  = lane & 15;
    const int quad = lane >> 4;

    // ---- prologue: stage full B into LDS (8 KB per wave), plus small tables ----
    {
        const char* gp = (const char*)W1p + wave * 8192 + lane * 16;
        char*       lp = (char*)&Bf[0] + wave * 8192 + lane * 16 - lane * 16; // uniform base
        lp = (char*)&Bf[0] + wave * 8192;
        #pragma unroll
        for (int i = 0; i < 8; i++) load_lds_1k(gp + i * 1024, lp + i * 1024);
    }
    if (p == 1) {   // waves 1,5,9,13: stage round-0 target vector for their group
        int e0 = blk * 8 + g; if (e0 >= Btot) e0 = Btot - 1;
        const int tg0 = target[e0], tr0 = target_region[e0];
        float4 v;
        if (lane < 32) v = *(const float4*)(E_tgt + (size_t)tg0 * DD + lane * 4);
        else           v = *(const float4*)(E_reg + (size_t)tr0 * DD + (lane - 32) * 4);
        *(float4*)(&tgts[0][g][lane * 4]) = v;
    }
    if (wave == 2) {
        *(float4*)(b1s + lane * 4) = *(const float4*)(b1 + lane * 4);
        *(float4*)(w2s + lane * 4) = *(const float4*)(w2 + lane * 4);
    }
    if (wave == 3) {
        float v = E_dist[lane] + E_dist[64 + lane];
        #pragma unroll
        for (int off = 32; off; off >>= 1) v += __shfl_xor(v, off);
        if (lane == 0) s_sumE = v;
    }
    __syncthreads();   // B + tgts[0] + b1s/w2s + s_sumE all visible

    // ---- main loop: 2 rounds, 4 elements in flight (one per group) ----
    #pragma unroll 1
    for (int r = 0; r < 2; r++) {
        const int par = r & 1;
        int e = blk * 8 + r * 4 + g; if (e >= Btot) e = Btot - 1;

        // index loads for this wave's two m-tiles (pad rows 100..127 -> row-64: L1-hot)
        const int row0 = p * 32 + col,       rc0 = (row0 < HH) ? row0 : row0 - 64;
        const int row1 = p * 32 + 16 + col,  rc1 = (row1 < HH) ? row1 : row1 - 64;
        const int ih0 = history[(size_t)e * HH + rc0];
        const int ir0 = history_region[(size_t)e * HH + rc0];
        const int ih1 = history[(size_t)e * HH + rc1];
        const int ir1 = history_region[(size_t)e * HH + rc1];

        // ---- gather into MFMA A-fragments (k = s*32 + quad*8 + j) ----
        bf16x8 afrag[2][8];
        float xs[2];
        #pragma unroll
        for (int mt = 0; mt < 2; mt++) {
            const float* ph = E_hist + (size_t)(mt ? ih1 : ih0) * DD + quad * 8;
            const float* pr = E_reg  + (size_t)(mt ? ir1 : ir0) * DD + quad * 8;
            float acc = 0.f;
            #pragma unroll
            for (int c = 0; c < 2; c++) {            // chunk: 4 s-steps, 8 float4 in flight
                #pragma unroll
                for (int si = 0; si < 4; si++) {
                    const int s = c * 4 + si;
                    const float* src = (s < 4) ? (ph + s * 32) : (pr + (s - 4) * 32);
                    float4 v0 = *(const float4*)src;
                    float4 v1 = *(const float4*)(src + 4);
                    const float* tp = &tgts[par][g][s * 32 + quad * 8];
                    float4 t0 = *(const float4*)tp, t1 = *(const float4*)(tp + 4);
                    float x0 = v0.x * t0.x, x1 = v0.y * t0.y, x2 = v0.z * t0.z, x3 = v0.w * t0.w;
                    float x4 = v1.x * t1.x, x5 = v1.y * t1.y, x6 = v1.z * t1.z, x7 = v1.w * t1.w;
                    acc += (x0 + x1) + (x2 + x3) + ((x4 + x5) + (x6 + x7));
                    union { unsigned short u[8]; bf16x8 v; } fb;
                    fb.u[0] = f2bf(x0); fb.u[1] = f2bf(x1); fb.u[2] = f2bf(x2); fb.u[3] = f2bf(x3);
                    fb.u[4] = f2bf(x4); fb.u[5] = f2bf(x5); fb.u[6] = f2bf(x6); fb.u[7] = f2bf(x7);
                    afrag[mt][s] = fb.v;
                }
                asm volatile("" ::: "memory");       // cap in-flight loads (spill guard)
            }
            xs[mt] = acc;
        }
        // xsum: reduce across quads; rows >= HH never read downstream
        #pragma unroll
        for (int mt = 0; mt < 2; mt++) {
            float v = xs[mt];
            v += __shfl_xor(v, 16);
            v += __shfl_xor(v, 32);
            if (quad == 0) xsum4[par][g][p * 32 + mt * 16 + col] = v;
        }

        // ---- MFMA vs LDS-resident B: 16 strips x 8 k-steps, 2 m-tiles ----
        float sacc[2][4] = {};
        #pragma unroll 4
        for (int st = 0; st < 16; st++) {
            const float bb = b1s[st * 16 + col];
            const float ww = w2s[st * 16 + col];
            f32x4 acc0 = {0.f, 0.f, 0.f, 0.f};
            f32x4 acc1 = {0.f, 0.f, 0.f, 0.f};
            #pragma unroll
            for (int s = 0; s < 8; s++) {
                bf16x8 bfrag = *(const bf16x8*)(Bf + ((st * 8 + s) * 64 + lane) * 8);
                acc0 = __builtin_amdgcn_mfma_f32_16x16x32_bf16(afrag[0][s], bfrag, acc0, 0, 0, 0);
                acc1 = __builtin_amdgcn_mfma_f32_16x16x32_bf16(afrag[1][s], bfrag, acc1, 0, 0, 0);
            }
            #pragma unroll
            for (int rr = 0; rr < 4; rr++) {
                float z0 = acc0[rr] + bb; sacc[0][rr] += (z0 > 0.f) ? z0 * ww : 0.f;
                float z1 = acc1[rr] + bb; sacc[1][rr] += (z1 > 0.f) ? z1 * ww : 0.f;
            }
        }
        // column reduction (lane bits 0..3); wave owns all cols -> score complete
        #pragma unroll
        for (int mt = 0; mt < 2; mt++) {
            #pragma unroll
            for (int rr = 0; rr < 4; rr++) {
                float z = sacc[mt][rr];
                z += __shfl_xor(z, 1);
                z += __shfl_xor(z, 2);
                z += __shfl_xor(z, 4);
                z += __shfl_xor(z, 8);
                sacc[mt][rr] = z;
            }
        }
        if (col == 0) {
            #pragma unroll
            for (int mt = 0; mt < 2; mt++)
                #pragma unroll
                for (int rr = 0; rr < 4; rr++)
                    score4[par][g][p * 32 + mt * 16 + quad * 4 + rr] = sacc[mt][rr];
        }

        // stage next round's target vector (waves p==1, during round 0)
        if (r == 0 && p == 1) {
            int e1 = blk * 8 + 4 + g; if (e1 >= Btot) e1 = Btot - 1;
            const int tg1 = target[e1], tr1 = target_region[e1];
            float4 v;
            if (lane < 32) v = *(const float4*)(E_tgt + (size_t)tg1 * DD + lane * 4);
            else           v = *(const float4*)(E_reg + (size_t)tr1 * DD + (lane - 32) * 4);
            *(float4*)(&tgts[1][g][lane * 4]) = v;
        }

        __syncthreads();   // score/xsum for round r complete; tgts[r+1] staged

        // ---- phase 3: one wave per group (p==0); others run ahead to next round ----
        if (p == 0) {
            const int eo = blk * 8 + r * 4 + g;
            if (eo < Btot) {
                const int   tg = target[eo];
                const float td = target_distance[eo];
                const float dist = td * s_sumE;
                float sc1 = score4[par][g][lane];
                float xv1 = xsum4[par][g][lane];
                int   hi1 = history[(size_t)eo * HH + lane];
                float e1 = (hi1 != tg) ? expf(sc1 + dist) : 0.f;
                float e2 = 0.f, xv2 = 0.f;
                if (lane + 64 < HH) {
                    float sc2 = score4[par][g][lane + 64];
                    xv2 = xsum4[par][g][lane + 64];
                    int hi2 = history[(size_t)eo * HH + lane + 64];
                    e2 = (hi2 != tg) ? expf(sc2 + dist) : 0.f;
                }
                float s1 = e1 + e2;
                float s2 = e1 * xv1 + e2 * xv2;
                #pragma unroll
                for (int off = 32; off; off >>= 1) {
                    s1 += __shfl_xor(s1, off);
                    s2 += __shfl_xor(s2, off);
                }
                if (lane == 0) {
                    float pred = s2 / sqrtf(s1);   // exp_sum^0.5 (BETA=0.5)
                    out[eo] = 1.f / (1.f + expf(-pred));
                }
            }
        }
    }
}

extern "C" void kernel_launch(void* const* d_in, const int* in_sizes, int n_in,
                              void* d_out, int out_size, void* d_ws, size_t ws_size,
                              hipStream_t stream) {
    const int*   history         = (const int*)d_in[0];
    const int*   target          = (const int*)d_in[1];
    const int*   history_region  = (const int*)d_in[2];
    const int*   target_region   = (const int*)d_in[3];
    const float* target_distance = (const float*)d_in[4];
    const float* E_hist          = (const float*)d_in[5];
    const float* E_tgt           = (const float*)d_in[6];
    const float* E_reg           = (const float*)d_in[7];
    const float* E_dist          = (const float*)d_in[8];
    const float* W1              = (const float*)d_in[9];
    const float* b1              = (const float*)d_in[10];
    const float* w2              = (const float*)d_in[11];

    unsigned short* W1p = (unsigned short*)d_ws;  // 131072 B
    const int B = in_sizes[1];
    const int blocks = (B + 7) / 8;

    w1_pack<<<32, 256, 0, stream>>>(W1, W1p);
    nais_kernel<<<blocks, 1024, 0, stream>>>(history, target, history_region, target_region,
                                             target_distance, E_hist, E_tgt, E_reg, E_dist,
                                             b1, w2, W1p, (float*)d_out, B);
}

// Round 11
// 192.621 us; speedup vs baseline: 1.4348x; 1.4348x over previous
//
#include <hip/hip_runtime.h>
#include <stdint.h>

typedef __attribute__((ext_vector_type(8))) short bf16x8;
typedef __attribute__((ext_vector_type(4))) float f32x4;

#define HH  100   // history length
#define DD  128   // embedding dim d
#define HID 256   // hidden width / concat dim

__device__ __forceinline__ unsigned short f2bf(float f) {
    unsigned int u = __float_as_uint(f);
    u += 0x7fffu + ((u >> 16) & 1u);   // round-to-nearest-even
    return (unsigned short)(u >> 16);
}

// async 1 KB global->LDS per wave: per-lane 16 B from g+lane*16, LDS at uniform base + lane*16
__device__ __forceinline__ void load_lds_1k(const void* g, void* l) {
    __builtin_amdgcn_global_load_lds((const __attribute__((address_space(1))) unsigned int*)g,
                                     (__attribute__((address_space(3))) unsigned int*)l,
                                     16, 0, 0);
}

// Pack W1 (256x256 f32, [n][k]) into MFMA B-fragment order, bf16 (RNE — runs once).
// unit = (st*8+s)*64 + lane holds W1[st*16 + (lane&15)][s*32 + (lane>>4)*8 + j], j=0..7
__global__ void w1_pack(const float* __restrict__ W1, unsigned short* __restrict__ W1p) {
    int unit = blockIdx.x * 256 + threadIdx.x;   // 0..8191
    int lane = unit & 63;
    int s    = (unit >> 6) & 7;
    int st   = unit >> 9;
    int col  = lane & 15, quad = lane >> 4;
    const float* src = W1 + (size_t)(st * 16 + col) * HID + s * 32 + quad * 8;
    union { unsigned short u[8]; bf16x8 v; } o;
    #pragma unroll
    for (int j = 0; j < 8; j++) o.u[j] = f2bf(src[j]);
    *(bf16x8*)(W1p + (size_t)unit * 8) = o.v;
}

// 512-thread block = 8 waves, ONE element per block, one 16-row m-tile per wave.
// Halved per-wave register footprint (afrag[8]=32 VGPR, single f32x4 acc) to test
// the unified VGPR+AGPR occupancy-cap hypothesis: (512,4) -> 128 regs/wave total
// -> 4 waves/SIMD -> 2 blocks/CU (50% occ) vs the chronic ~20% of the 64-reg-afrag
// shape. Spill guard: gather loads chunked at 8 float4 in flight.
__global__ __launch_bounds__(512, 4) void nais_kernel(
    const int* __restrict__ history,           // [B,HH]
    const int* __restrict__ target,            // [B]
    const int* __restrict__ history_region,    // [B,HH]
    const int* __restrict__ target_region,     // [B]
    const float* __restrict__ target_distance, // [B]
    const float* __restrict__ E_hist,          // [item,128]
    const float* __restrict__ E_tgt,           // [item,128]
    const float* __restrict__ E_reg,           // [region,128]
    const float* __restrict__ E_dist,          // [16,128]
    const float* __restrict__ b1,              // [256]
    const float* __restrict__ w2,              // [256]
    const unsigned short* __restrict__ W1p,    // packed bf16 B-fragments (128 KB)
    float* __restrict__ out)                   // [B]
{
    // B-stage: 8 stages x 16 KB (2 st-strips each), double-buffered = 32 KB
    __shared__ __align__(16) unsigned short Bs[2][8192];
    __shared__ __align__(16) float tgts[HID];
    __shared__ __align__(16) float b1s[HID];
    __shared__ __align__(16) float w2s[HID];
    __shared__ float score[128];
    __shared__ float xsum[128];
    __shared__ float eA[HH];
    __shared__ float exs[HH];
    __shared__ int hidx[HH];
    __shared__ int hreg[HH];
    __shared__ float s_sumE;

    const int b    = blockIdx.x;
    const int t    = threadIdx.x;
    const int lane = t & 63;
    const int wave = t >> 6;                   // 0..7, owns rows 16w..16w+15
    const int col  = lane & 15;
    const int quad = lane >> 4;

    const int   tg    = target[b];
    const float tdist = target_distance[b];

    // ---- phase 0: stage indices, tgt vector, b1/w2, sum(E_dist[0]) ----
    if (t < HH) {
        hidx[t] = history[b * HH + t];
        hreg[t] = history_region[b * HH + t];
    }
    if (wave == 4) {
        float4 v;
        if (lane < 32) v = *(const float4*)(E_tgt + (size_t)tg * DD + lane * 4);
        else           v = *(const float4*)(E_reg + (size_t)target_region[b] * DD + (lane - 32) * 4);
        *(float4*)(tgts + lane * 4) = v;
    }
    if (wave == 5) {
        *(float4*)(b1s + lane * 4) = *(const float4*)(b1 + lane * 4);
        *(float4*)(w2s + lane * 4) = *(const float4*)(w2 + lane * 4);
    }
    if (wave == 6) {
        float v = E_dist[lane] + E_dist[64 + lane];
        #pragma unroll
        for (int off = 32; off; off >>= 1) v += __shfl_xor(v, off);
        if (lane == 0) s_sumE = v;
    }
    __syncthreads();

    // issue stage-0 B load (async; overlaps the gather phase). 16 KB / 8 waves.
    {
        const char* g = (const char*)W1p + wave * 2048 + lane * 16;
        char*       l = (char*)&Bs[0][0] + wave * 2048;
        load_lds_1k(g, l);
        load_lds_1k(g + 1024, l + 1024);
    }

    // ---- phase 1: gather E-row into MFMA A-fragment layout (one m-tile/wave) ----
    // row = 16*wave + col; pad rows 100..127 clamp to row-64 (rows 36..63: L2-hot
    // re-reads, no predication VALU, never read downstream).
    // A-frag element: lane(col,quad), k = s*32 + quad*8 + j  (s<4: E_hist, s>=4: E_reg)
    const int row = wave * 16 + col;
    const int rc  = (row < HH) ? row : row - 64;
    const int ih  = hidx[rc];
    const int ir  = hreg[rc];
    const float* ph = E_hist + (size_t)ih * DD + quad * 8;
    const float* pr = E_reg  + (size_t)ir * DD + quad * 8;
    bf16x8 afrag[8];
    float acc = 0.f;
    #pragma unroll
    for (int c = 0; c < 2; c++) {            // chunk: 4 s-steps, 8 float4 in flight
        #pragma unroll
        for (int si = 0; si < 4; si++) {
            const int s = c * 4 + si;
            const float* src = (s < 4) ? (ph + s * 32) : (pr + (s - 4) * 32);
            float4 v0 = *(const float4*)src;
            float4 v1 = *(const float4*)(src + 4);
            const float* tp = tgts + s * 32 + quad * 8;  // broadcast across cols
            float4 t0 = *(const float4*)tp, t1 = *(const float4*)(tp + 4);
            float x0 = v0.x * t0.x, x1 = v0.y * t0.y, x2 = v0.z * t0.z, x3 = v0.w * t0.w;
            float x4 = v1.x * t1.x, x5 = v1.y * t1.y, x6 = v1.z * t1.z, x7 = v1.w * t1.w;
            acc += (x0 + x1) + (x2 + x3) + ((x4 + x5) + (x6 + x7));
            union { unsigned short u[8]; bf16x8 v; } fb;
            fb.u[0] = f2bf(x0); fb.u[1] = f2bf(x1); fb.u[2] = f2bf(x2); fb.u[3] = f2bf(x3);
            fb.u[4] = f2bf(x4); fb.u[5] = f2bf(x5); fb.u[6] = f2bf(x6); fb.u[7] = f2bf(x7);
            afrag[s] = fb.v;
        }
        asm volatile("" ::: "memory");       // cap in-flight loads (spill guard)
    }
    // xsum[row] = sum over k: reduce across the 4 quads (lane bits 4,5)
    {
        float v = acc;
        v += __shfl_xor(v, 16);
        v += __shfl_xor(v, 32);
        if (quad == 0) xsum[row] = v;        // rows >= HH written, never read
    }

    // ---- phase 2: score = relu(X @ W1^T + b1) . w2 via MFMA, B staged thru LDS ----
    // stage k holds st in {2k, 2k+1}; barrier-per-stage double buffer.
    float sacc[4] = {};
    #pragma unroll 1
    for (int k = 0; k < 8; k++) {
        __syncthreads();
        if (k < 7) {
            const char* g = (const char*)W1p + (k + 1) * 16384 + wave * 2048 + lane * 16;
            char*       l = (char*)&Bs[(k + 1) & 1][0] + wave * 2048;
            load_lds_1k(g, l);
            load_lds_1k(g + 1024, l + 1024);
        }
        const unsigned short* buf = &Bs[k & 1][0];
        #pragma unroll
        for (int sti = 0; sti < 2; sti++) {
            const int st = k * 2 + sti;
            const float bb = b1s[st * 16 + col];
            const float ww = w2s[st * 16 + col];
            f32x4 acc0 = {0.f, 0.f, 0.f, 0.f};
            #pragma unroll
            for (int s = 0; s < 8; s++) {
                bf16x8 bfrag = *(const bf16x8*)(buf + ((sti * 8 + s) * 64 + lane) * 8);
                acc0 = __builtin_amdgcn_mfma_f32_16x16x32_bf16(afrag[s], bfrag, acc0, 0, 0, 0);
            }
            #pragma unroll
            for (int r = 0; r < 4; r++) {
                float z = acc0[r] + bb;
                sacc[r] += (z > 0.f) ? z * ww : 0.f;
            }
        }
    }
    // column reduction over the 16 cols (lane bits 0..3); wave owns all cols
    #pragma unroll
    for (int r = 0; r < 4; r++) {
        float z = sacc[r];
        z += __shfl_xor(z, 1);
        z += __shfl_xor(z, 2);
        z += __shfl_xor(z, 4);
        z += __shfl_xor(z, 8);
        sacc[r] = z;
    }
    if (col == 0) {
        #pragma unroll
        for (int r = 0; r < 4; r++)
            score[wave * 16 + quad * 4 + r] = sacc[r];
    }

    __syncthreads();

    // ---- phase 3: masked exp, denom^BETA, weighted sum, sigmoid ----
    const float dist = tdist * s_sumE;
    if (t < HH) {
        float e = (hidx[t] != tg) ? expf(score[t] + dist) : 0.f;
        eA[t]  = e;
        exs[t] = e * xsum[t];
    }
    __syncthreads();
    if (t < 64) {
        float s1 = eA[t]  + ((t + 64 < HH) ? eA[t + 64]  : 0.f);
        float s2 = exs[t] + ((t + 64 < HH) ? exs[t + 64] : 0.f);
        #pragma unroll
        for (int off = 32; off; off >>= 1) {
            s1 += __shfl_xor(s1, off);
            s2 += __shfl_xor(s2, off);
        }
        if (t == 0) {
            float pred = s2 / sqrtf(s1);   // exp_sum^0.5 (BETA=0.5)
            out[b] = 1.f / (1.f + expf(-pred));
        }
    }
}

extern "C" void kernel_launch(void* const* d_in, const int* in_sizes, int n_in,
                              void* d_out, int out_size, void* d_ws, size_t ws_size,
                              hipStream_t stream) {
    const int*   history         = (const int*)d_in[0];
    const int*   target          = (const int*)d_in[1];
    const int*   history_region  = (const int*)d_in[2];
    const int*   target_region   = (const int*)d_in[3];
    const float* target_distance = (const float*)d_in[4];
    const float* E_hist          = (const float*)d_in[5];
    const float* E_tgt           = (const float*)d_in[6];
    const float* E_reg           = (const float*)d_in[7];
    const float* E_dist          = (const float*)d_in[8];
    const float* W1              = (const float*)d_in[9];
    const float* b1              = (const float*)d_in[10];
    const float* w2              = (const float*)d_in[11];

    unsigned short* W1p = (unsigned short*)d_ws;  // 131072 B
    const int B = in_sizes[1];

    w1_pack<<<32, 256, 0, stream>>>(W1, W1p);
    nais_kernel<<<B, 512, 0, stream>>>(history, target, history_region, target_region,
                                       target_distance, E_hist, E_tgt, E_reg, E_dist,
                                       b1, w2, W1p, (float*)d_out);
}